// Round 1
// 222.592 us; speedup vs baseline: 1.0770x; 1.0770x over previous
//
#include <hip/hip_runtime.h>
#include <hip/hip_bf16.h>

typedef unsigned short u16;
typedef __bf16 bf16x8 __attribute__((ext_vector_type(8)));
typedef float f32x4 __attribute__((ext_vector_type(4)));
typedef unsigned short u16x8 __attribute__((ext_vector_type(8)));
typedef unsigned short u16x4 __attribute__((ext_vector_type(4)));

// round-to-nearest-even fp32 -> bf16
__device__ inline u16 f2bf(float f) {
    union { float f; unsigned u; } v; v.f = f;
    unsigned r = v.u + 0x7fffu + ((v.u >> 16) & 1u);
    return (u16)(r >> 16);
}

__device__ inline float bf2f(u16 b) {
    union { unsigned u; float f; } v; v.u = ((unsigned)b) << 16;
    return v.f;
}

// ---------------------------------------------------------------------------
// Convert x and 4 weights to bf16, contiguous in ws:
//   [x_bf 4194304][wq 1048576][wk][wv][wo]
// ---------------------------------------------------------------------------
__global__ void convert_kernel(const float* __restrict__ x,
                               const float* __restrict__ wq, const float* __restrict__ wk,
                               const float* __restrict__ wv, const float* __restrict__ wo,
                               u16* __restrict__ dst) {
    long g = (long)blockIdx.x * blockDim.x + threadIdx.x;  // group of 4 elements
    const float* src; long base;
    const long GX = 1048576, GW = 262144;  // groups: x = 4.19M els, each w = 1.05M els
    if (g < GX)            { src = x;  base = 0; }
    else if (g < GX + GW)  { src = wq; base = GX; }
    else if (g < GX + 2*GW){ src = wk; base = GX + GW; }
    else if (g < GX + 3*GW){ src = wv; base = GX + 2*GW; }
    else                   { src = wo; base = GX + 3*GW; }
    long rel = g - base;
    float4 v = reinterpret_cast<const float4*>(src)[rel];
    ushort4 o;
    o.x = f2bf(v.x); o.y = f2bf(v.y); o.z = f2bf(v.z); o.w = f2bf(v.w);
    reinterpret_cast<ushort4*>(dst)[g] = o;
}

// ---------------------------------------------------------------------------
// Shared GEMM mainloop: C[128x128] tile of A[T][1024] * W[N][1024]^T.
// 256 threads = 4 waves (2x2), each wave 64x64 via 4x4 frags of 16x16x32 bf16.
// LDS rows padded to 72 els (144 B, 16B-aligned, conflict-free-ish).
// ---------------------------------------------------------------------------
#define LDP 72

__device__ inline void gemm_mainloop(const u16* __restrict__ A, const u16* __restrict__ W,
                                     int t0, int n0, u16* As, u16* Bs, f32x4 acc[4][4]) {
    const int tid = threadIdx.x;
    const int wid = tid >> 6, lane = tid & 63, quad = lane >> 4, ln = lane & 15;
    const int wm = wid >> 1, wn = wid & 1;
#pragma unroll
    for (int im = 0; im < 4; im++)
#pragma unroll
        for (int in = 0; in < 4; in++) acc[im][in] = (f32x4){0.f, 0.f, 0.f, 0.f};

    for (int k0 = 0; k0 < 1024; k0 += 64) {
#pragma unroll
        for (int i = 0; i < 4; i++) {
            int c = i * 256 + tid;       // 1024 chunks of 8 bf16
            int row = c >> 3, kc = c & 7;
            u16x8 av = *reinterpret_cast<const u16x8*>(A + (long)(t0 + row) * 1024 + k0 + kc * 8);
            u16x8 bv = *reinterpret_cast<const u16x8*>(W + (long)(n0 + row) * 1024 + k0 + kc * 8);
            *reinterpret_cast<u16x8*>(As + row * LDP + kc * 8) = av;
            *reinterpret_cast<u16x8*>(Bs + row * LDP + kc * 8) = bv;
        }
        __syncthreads();
#pragma unroll
        for (int ks = 0; ks < 2; ks++) {
            bf16x8 af[4], bf[4];
#pragma unroll
            for (int im = 0; im < 4; im++)
                af[im] = *reinterpret_cast<const bf16x8*>(As + (wm * 64 + im * 16 + ln) * LDP + ks * 32 + quad * 8);
#pragma unroll
            for (int in = 0; in < 4; in++)
                bf[in] = *reinterpret_cast<const bf16x8*>(Bs + (wn * 64 + in * 16 + ln) * LDP + ks * 32 + quad * 8);
#pragma unroll
            for (int im = 0; im < 4; im++)
#pragma unroll
                for (int in = 0; in < 4; in++)
                    acc[im][in] = __builtin_amdgcn_mfma_f32_16x16x32_bf16(af[im], bf[in], acc[im][in], 0, 0, 0);
        }
        __syncthreads();
    }
}

// ---------------------------------------------------------------------------
// QKV projection. z = 0:q, 1:k, 2:v.
//   q_ws/k_ws: [bh][s][64] bf16 (q pre-scaled by 1/8 for the softmax scale)
//   v_ws:      [bh][64][s] bf16 (transposed so attention PV B-frags are contiguous)
// ---------------------------------------------------------------------------
__global__ void qkv_gemm(const u16* __restrict__ x_bf,
                         const u16* __restrict__ wq, const u16* __restrict__ wk, const u16* __restrict__ wv,
                         const float* __restrict__ sq, const float* __restrict__ sk, const float* __restrict__ sv,
                         const float* __restrict__ bq, const float* __restrict__ bk, const float* __restrict__ bv,
                         u16* __restrict__ q_ws, u16* __restrict__ k_ws, u16* __restrict__ v_ws) {
    __shared__ u16 As[128 * LDP];
    __shared__ u16 Bs[128 * LDP];
    const int z = blockIdx.z;
    const u16* W   = (z == 0) ? wq : (z == 1) ? wk : wv;
    const float* sp = (z == 0) ? sq : (z == 1) ? sk : sv;
    const float* bp = (z == 0) ? bq : (z == 1) ? bk : bv;
    u16* dst = (z == 0) ? q_ws : (z == 1) ? k_ws : v_ws;
    const float extra = (z == 0) ? 0.125f : 1.0f;   // fold 1/sqrt(64) into q
    const int t0 = blockIdx.x * 128, n0 = blockIdx.y * 128;

    f32x4 acc[4][4];
    gemm_mainloop(x_bf, W, t0, n0, As, Bs, acc);

    const int tid = threadIdx.x;
    const int wid = tid >> 6, lane = tid & 63, quad = lane >> 4, ln = lane & 15;
    const int wm = wid >> 1, wn = wid & 1;
    const float s = sp[0] * extra;
#pragma unroll
    for (int in = 0; in < 4; in++) {
        int col = n0 + wn * 64 + in * 16 + ln;
        float bias = bp[col] * extra;
        int h = col >> 6, d = col & 63;
#pragma unroll
        for (int im = 0; im < 4; im++) {
            int rbase = t0 + wm * 64 + im * 16 + quad * 4;
#pragma unroll
            for (int j = 0; j < 4; j++) {
                int t = rbase + j;
                int b = t >> 11, ss = t & 2047;
                int bh = b * 16 + h;
                float val = acc[im][in][j] * s + bias;
                long idx = (z < 2) ? ((long)(bh * 2048 + ss) * 64 + d)
                                   : ((long)(bh * 64 + d) * 2048 + ss);
                dst[idx] = f2bf(val);
            }
        }
    }
}

// ---------------------------------------------------------------------------
// Attention: per (q-tile of 128, bh). No-max softmax (scores bounded):
// accumulate exp(s)@V unnormalized; denominator as running f32 sum per q-row.
//
// Key structural points vs previous version:
//  - QK^T is computed SWAPPED: S^T = mfma(K_frag, Q_frag). Output lane
//    (quad,ln) then holds q=ln and 4 CONSECUTIVE keys (quad*4+j), so P can be
//    stored to Pt[q][key] with 8x ds_write_b64 instead of 32x ds_write_b16.
//  - Denominator l = running f32 sum of the (bf16-rounded) P values per lane
//    (each lane owns a full 16-key slice of its q-row); cross-quad reduce at
//    the end. Removes the ones-row MFMA path + its Vt tail + 2 LDS reads/iter.
//  - K/V staging is prefetched into registers one tile ahead (issue loads
//    before the barrier, consume next iteration) to hide global latency.
// ---------------------------------------------------------------------------
__global__ void attn_kernel(const u16* __restrict__ q_ws, const u16* __restrict__ k_ws,
                            const u16* __restrict__ v_ws, u16* __restrict__ ctx) {
    __shared__ u16 Kt[64 * LDP];    // [key][d]
    __shared__ u16 Vt[64 * LDP];    // [d][key]
    __shared__ u16 Pt[128 * LDP];   // [q][key] exp(scores) in bf16

    const int tid = threadIdx.x;
    const int wid = tid >> 6, lane = tid & 63, quad = lane >> 4, ln = lane & 15;
    const int bh = blockIdx.y;
    const int q0 = blockIdx.x * 128;
    const u16* qbase = q_ws + (long)bh * 2048 * 64;
    const u16* kbase = k_ws + (long)bh * 2048 * 64;
    const u16* vbase = v_ws + (long)bh * 64 * 2048;

    // Q fragments held in registers for the whole K loop (q pre-scaled by 1/8)
    bf16x8 aq[2][2];
#pragma unroll
    for (int qt = 0; qt < 2; qt++)
#pragma unroll
        for (int ks = 0; ks < 2; ks++)
            aq[qt][ks] = *reinterpret_cast<const bf16x8*>(
                qbase + (long)(q0 + wid * 32 + qt * 16 + ln) * 64 + ks * 32 + quad * 8);

    f32x4 acc_o[2][4];
    float lsum[2] = {0.f, 0.f};
#pragma unroll
    for (int qt = 0; qt < 2; qt++)
#pragma unroll
        for (int dt = 0; dt < 4; dt++) acc_o[qt][dt] = (f32x4){0.f, 0.f, 0.f, 0.f};

    // prefetch first K/V tile into registers
    u16x8 kreg[2], vreg[2];
#pragma unroll
    for (int i = 0; i < 2; i++) {
        int c = i * 256 + tid;
        int row = c >> 3, kc = c & 7;
        kreg[i] = *reinterpret_cast<const u16x8*>(kbase + (long)row * 64 + kc * 8);
        vreg[i] = *reinterpret_cast<const u16x8*>(vbase + (long)row * 2048 + kc * 8);
    }

    for (int kt = 0; kt < 2048; kt += 64) {
        // write staged regs to LDS, then immediately issue next tile's loads so
        // their latency hides under this tile's compute
#pragma unroll
        for (int i = 0; i < 2; i++) {
            int c = i * 256 + tid;
            int row = c >> 3, kc = c & 7;
            *reinterpret_cast<u16x8*>(Kt + row * LDP + kc * 8) = kreg[i];
            *reinterpret_cast<u16x8*>(Vt + row * LDP + kc * 8) = vreg[i];
        }
        if (kt + 64 < 2048) {
#pragma unroll
            for (int i = 0; i < 2; i++) {
                int c = i * 256 + tid;
                int row = c >> 3, kc = c & 7;
                kreg[i] = *reinterpret_cast<const u16x8*>(kbase + (long)(kt + 64 + row) * 64 + kc * 8);
                vreg[i] = *reinterpret_cast<const u16x8*>(vbase + (long)row * 2048 + (kt + 64) + kc * 8);
            }
        }
        __syncthreads();

        // S^T = K Q^T (swapped operands). Lane (quad,ln): q = ln,
        // keys = k8*16 + quad*4 + j  -> 4 consecutive keys per lane.
#pragma unroll
        for (int k8 = 0; k8 < 4; k8++) {
            bf16x8 a0 = *reinterpret_cast<const bf16x8*>(Kt + (k8 * 16 + ln) * LDP + quad * 8);
            bf16x8 a1 = *reinterpret_cast<const bf16x8*>(Kt + (k8 * 16 + ln) * LDP + 32 + quad * 8);
#pragma unroll
            for (int qt = 0; qt < 2; qt++) {
                f32x4 t = (f32x4){0.f, 0.f, 0.f, 0.f};
                t = __builtin_amdgcn_mfma_f32_16x16x32_bf16(a0, aq[qt][0], t, 0, 0, 0);
                t = __builtin_amdgcn_mfma_f32_16x16x32_bf16(a1, aq[qt][1], t, 0, 0, 0);
                float p0 = __expf(t[0]), p1 = __expf(t[1]), p2 = __expf(t[2]), p3 = __expf(t[3]);
                u16x4 w;
                w.x = f2bf(p0); w.y = f2bf(p1); w.z = f2bf(p2); w.w = f2bf(p3);
                // sum the rounded values so numerator/denominator stay consistent
                lsum[qt] += bf2f(w.x) + bf2f(w.y) + bf2f(w.z) + bf2f(w.w);
                *reinterpret_cast<u16x4*>(
                    Pt + (wid * 32 + qt * 16 + ln) * LDP + k8 * 16 + quad * 4) = w;
            }
        }

        // O += P V   (A-frag reads of Pt are wave-local rows: no barrier needed)
#pragma unroll
        for (int step = 0; step < 2; step++) {
            bf16x8 ap[2];
#pragma unroll
            for (int qt = 0; qt < 2; qt++)
                ap[qt] = *reinterpret_cast<const bf16x8*>(
                    Pt + (wid * 32 + qt * 16 + ln) * LDP + step * 32 + quad * 8);
#pragma unroll
            for (int dt = 0; dt < 4; dt++) {
                bf16x8 bv = *reinterpret_cast<const bf16x8*>(
                    Vt + (dt * 16 + ln) * LDP + step * 32 + quad * 8);
#pragma unroll
                for (int qt = 0; qt < 2; qt++)
                    acc_o[qt][dt] = __builtin_amdgcn_mfma_f32_16x16x32_bf16(ap[qt], bv, acc_o[qt][dt], 0, 0, 0);
            }
        }
        __syncthreads();
    }

    // finalize denominator and write ctx [t][h*64+d] bf16
    const int b = bh >> 4, h = bh & 15;
#pragma unroll
    for (int qt = 0; qt < 2; qt++) {
        // lane (quad,ln) has partial sum (16 keys/iter) for q-row ln; reduce quads
        float lt = lsum[qt];
        lt += __shfl_xor(lt, 16, 64);
        lt += __shfl_xor(lt, 32, 64);
        // lt now = full denominator for q = q0 + wid*32 + qt*16 + ln (all lanes)
#pragma unroll
        for (int j = 0; j < 4; j++) {
            // acc_o rows live at q = quad*4 + j; fetch matching denominator
            float rinv = 1.0f / __shfl(lt, quad * 4 + j, 64);
            int t = b * 2048 + q0 + wid * 32 + qt * 16 + quad * 4 + j;
#pragma unroll
            for (int dt = 0; dt < 4; dt++) {
                float val = acc_o[qt][dt][j] * rinv;
                ctx[(long)t * 1024 + h * 64 + dt * 16 + ln] = f2bf(val);
            }
        }
    }
}

// ---------------------------------------------------------------------------
// Output projection: d_out[t][o] = ctx @ wo^T * s_o + b_o  (fp32 out)
// ---------------------------------------------------------------------------
__global__ void o_gemm(const u16* __restrict__ ctx, const u16* __restrict__ wo,
                       const float* __restrict__ so, const float* __restrict__ bo,
                       float* __restrict__ out) {
    __shared__ u16 As[128 * LDP];
    __shared__ u16 Bs[128 * LDP];
    const int t0 = blockIdx.x * 128, n0 = blockIdx.y * 128;
    f32x4 acc[4][4];
    gemm_mainloop(ctx, wo, t0, n0, As, Bs, acc);

    const int tid = threadIdx.x;
    const int wid = tid >> 6, lane = tid & 63, quad = lane >> 4, ln = lane & 15;
    const int wm = wid >> 1, wn = wid & 1;
    const float s = so[0];
#pragma unroll
    for (int in = 0; in < 4; in++) {
        int col = n0 + wn * 64 + in * 16 + ln;
        float bias = bo[col];
#pragma unroll
        for (int im = 0; im < 4; im++) {
            int rbase = t0 + wm * 64 + im * 16 + quad * 4;
#pragma unroll
            for (int j = 0; j < 4; j++)
                out[(long)(rbase + j) * 1024 + col] = acc[im][in][j] * s + bias;
        }
    }
}

// ---------------------------------------------------------------------------
extern "C" void kernel_launch(void* const* d_in, const int* in_sizes, int n_in,
                              void* d_out, int out_size, void* d_ws, size_t ws_size,
                              hipStream_t stream) {
    const float* x   = (const float*)d_in[0];
    const float* w_q = (const float*)d_in[1];
    const float* s_q = (const float*)d_in[2];
    const float* b_q = (const float*)d_in[3];
    const float* w_k = (const float*)d_in[4];
    const float* s_k = (const float*)d_in[5];
    const float* b_k = (const float*)d_in[6];
    const float* w_v = (const float*)d_in[7];
    const float* s_v = (const float*)d_in[8];
    const float* b_v = (const float*)d_in[9];
    const float* w_o = (const float*)d_in[10];
    const float* s_o = (const float*)d_in[11];
    const float* b_o = (const float*)d_in[12];

    if (ws_size < (size_t)50331648) return;  // need 48 MB of scratch

    u16* ws     = (u16*)d_ws;
    u16* x_bf   = ws;                    // 4096*1024
    u16* wq_bf  = x_bf  + 4194304;       // 1024*1024 each
    u16* wk_bf  = wq_bf + 1048576;
    u16* wv_bf  = wk_bf + 1048576;
    u16* wo_bf  = wv_bf + 1048576;
    u16* q_ws   = wo_bf + 1048576;       // [32 bh][2048 s][64 d]
    u16* k_ws   = q_ws  + 4194304;
    u16* v_ws   = k_ws  + 4194304;       // [32 bh][64 d][2048 s]
    u16* ctx_ws = v_ws  + 4194304;       // [4096 t][1024]

    convert_kernel<<<dim3(8192), dim3(256), 0, stream>>>(x, w_q, w_k, w_v, w_o, ws);
    qkv_gemm<<<dim3(32, 8, 3), dim3(256), 0, stream>>>(x_bf, wq_bf, wk_bf, wv_bf,
                                                       s_q, s_k, s_v, b_q, b_k, b_v,
                                                       q_ws, k_ws, v_ws);
    attn_kernel<<<dim3(16, 32), dim3(256), 0, stream>>>(q_ws, k_ws, v_ws, ctx_ws);
    o_gemm<<<dim3(32, 8), dim3(256), 0, stream>>>(ctx_ws, wo_bf, s_o, b_o, (float*)d_out);
}

// Round 2
// 207.685 us; speedup vs baseline: 1.1544x; 1.0718x over previous
//
#include <hip/hip_runtime.h>
#include <hip/hip_bf16.h>

typedef unsigned short u16;
typedef __bf16 bf16x8 __attribute__((ext_vector_type(8)));
typedef __bf16 bf16x4 __attribute__((ext_vector_type(4)));
typedef float f32x4 __attribute__((ext_vector_type(4)));
typedef unsigned short u16x8 __attribute__((ext_vector_type(8)));

// round-to-nearest-even fp32 -> bf16 (epilogue paths only)
__device__ inline u16 f2bf(float f) {
    union { float f; unsigned u; } v; v.f = f;
    unsigned r = v.u + 0x7fffu + ((v.u >> 16) & 1u);
    return (u16)(r >> 16);
}

// ---------------------------------------------------------------------------
// Convert x and 4 weights to bf16, contiguous in ws:
//   [x_bf 4194304][wq 1048576][wk][wv][wo]
// ---------------------------------------------------------------------------
__global__ void convert_kernel(const float* __restrict__ x,
                               const float* __restrict__ wq, const float* __restrict__ wk,
                               const float* __restrict__ wv, const float* __restrict__ wo,
                               u16* __restrict__ dst) {
    long g = (long)blockIdx.x * blockDim.x + threadIdx.x;  // group of 4 elements
    const float* src; long base;
    const long GX = 1048576, GW = 262144;  // groups: x = 4.19M els, each w = 1.05M els
    if (g < GX)            { src = x;  base = 0; }
    else if (g < GX + GW)  { src = wq; base = GX; }
    else if (g < GX + 2*GW){ src = wk; base = GX + GW; }
    else if (g < GX + 3*GW){ src = wv; base = GX + 2*GW; }
    else                   { src = wo; base = GX + 3*GW; }
    long rel = g - base;
    float4 v = reinterpret_cast<const float4*>(src)[rel];
    ushort4 o;
    o.x = f2bf(v.x); o.y = f2bf(v.y); o.z = f2bf(v.z); o.w = f2bf(v.w);
    reinterpret_cast<ushort4*>(dst)[g] = o;
}

// ---------------------------------------------------------------------------
// Shared GEMM mainloop: C[128x128] tile of A[T][1024] * W[N][1024]^T.
// 256 threads = 4 waves (2x2), each wave 64x64 via 4x4 frags of 16x16x32 bf16.
//
// Staging: global_load_lds dwordx4 (no VGPR round-trip). LDS is LINEAR
// [128 rows][128 B]; bank uniformity comes from a st-16x32-style XOR swizzle
// (byte ^= (row&7)<<4) applied to the per-lane GLOBAL source address on the
// write side and to the fragment addresses on the read side (both-sides
// involution; global_load_lds dest must stay linear: base + lane*16).
// ---------------------------------------------------------------------------
__device__ inline void gemm_mainloop(const u16* __restrict__ A, const u16* __restrict__ W,
                                     int t0, int n0, u16* As, u16* Bs, f32x4 acc[4][4]) {
    const int tid = threadIdx.x;
    const int wid = tid >> 6, lane = tid & 63, quad = lane >> 4, ln = lane & 15;
    const int wm = wid >> 1, wn = wid & 1;
#pragma unroll
    for (int im = 0; im < 4; im++)
#pragma unroll
        for (int in = 0; in < 4; in++) acc[im][in] = (f32x4){0.f, 0.f, 0.f, 0.f};

    for (int k0 = 0; k0 < 1024; k0 += 64) {
        // stage A,B tiles: 16 chunks of 1 KB each per matrix, 4 per wave
#pragma unroll
        for (int i = 0; i < 4; i++) {
            int chunk = wid * 4 + i;                 // 0..15, wave-uniform
            int b = chunk * 1024 + lane * 16;        // linear LDS byte this lane fills
            int row = b >> 7;                        // tile row (128 B rows)
            int cb = (b & 127) ^ ((row & 7) << 4);   // pre-swizzled source column byte
            const u16* gA = A + (long)(t0 + row) * 1024 + k0 + (cb >> 1);
            const u16* gB = W + (long)(n0 + row) * 1024 + k0 + (cb >> 1);
            __builtin_amdgcn_global_load_lds((const __attribute__((address_space(1))) void*)gA,
                                             (__attribute__((address_space(3))) void*)(As + chunk * 512),
                                             16, 0, 0);
            __builtin_amdgcn_global_load_lds((const __attribute__((address_space(1))) void*)gB,
                                             (__attribute__((address_space(3))) void*)(Bs + chunk * 512),
                                             16, 0, 0);
        }
        __syncthreads();
#pragma unroll
        for (int ks = 0; ks < 2; ks++) {
            bf16x8 af[4], bfr[4];
#pragma unroll
            for (int im = 0; im < 4; im++) {
                int r = wm * 64 + im * 16 + ln;
                int byt = (r * 128 + ks * 64 + quad * 16) ^ ((r & 7) << 4);
                af[im] = *reinterpret_cast<const bf16x8*>((const char*)As + byt);
            }
#pragma unroll
            for (int in = 0; in < 4; in++) {
                int r = wn * 64 + in * 16 + ln;
                int byt = (r * 128 + ks * 64 + quad * 16) ^ ((r & 7) << 4);
                bfr[in] = *reinterpret_cast<const bf16x8*>((const char*)Bs + byt);
            }
#pragma unroll
            for (int im = 0; im < 4; im++)
#pragma unroll
                for (int in = 0; in < 4; in++)
                    acc[im][in] = __builtin_amdgcn_mfma_f32_16x16x32_bf16(af[im], bfr[in], acc[im][in], 0, 0, 0);
        }
        __syncthreads();
    }
}

// ---------------------------------------------------------------------------
// QKV projection. z = 0:q, 1:k, 2:v.
//   q_ws/k_ws: [bh][s][64] bf16 (q pre-scaled by log2(e)/8: folds the softmax
//              1/sqrt(64) AND the exp->exp2 conversion)
//   v_ws:      [bh][64][s] bf16 (transposed so attention PV B-frags are contiguous)
// ---------------------------------------------------------------------------
__global__ void qkv_gemm(const u16* __restrict__ x_bf,
                         const u16* __restrict__ wq, const u16* __restrict__ wk, const u16* __restrict__ wv,
                         const float* __restrict__ sq, const float* __restrict__ sk, const float* __restrict__ sv,
                         const float* __restrict__ bq, const float* __restrict__ bk, const float* __restrict__ bv,
                         u16* __restrict__ q_ws, u16* __restrict__ k_ws, u16* __restrict__ v_ws) {
    __shared__ __align__(16) u16 As[128 * 64];
    __shared__ __align__(16) u16 Bs[128 * 64];
    const int z = blockIdx.z;
    const u16* W   = (z == 0) ? wq : (z == 1) ? wk : wv;
    const float* sp = (z == 0) ? sq : (z == 1) ? sk : sv;
    const float* bp = (z == 0) ? bq : (z == 1) ? bk : bv;
    u16* dst = (z == 0) ? q_ws : (z == 1) ? k_ws : v_ws;
    // q gets 1/8 (softmax scale) * log2(e) (so attn can use exp2 natively)
    const float extra = (z == 0) ? 0.125f * 1.44269504088896f : 1.0f;
    const int t0 = blockIdx.x * 128, n0 = blockIdx.y * 128;

    f32x4 acc[4][4];
    gemm_mainloop(x_bf, W, t0, n0, As, Bs, acc);

    const int tid = threadIdx.x;
    const int wid = tid >> 6, lane = tid & 63, quad = lane >> 4, ln = lane & 15;
    const int wm = wid >> 1, wn = wid & 1;
    const float s = sp[0] * extra;
#pragma unroll
    for (int in = 0; in < 4; in++) {
        int col = n0 + wn * 64 + in * 16 + ln;
        float bias = bp[col] * extra;
        int h = col >> 6, d = col & 63;
#pragma unroll
        for (int im = 0; im < 4; im++) {
            int rbase = t0 + wm * 64 + im * 16 + quad * 4;
#pragma unroll
            for (int j = 0; j < 4; j++) {
                int t = rbase + j;
                int b = t >> 11, ss = t & 2047;
                int bh = b * 16 + h;
                float val = acc[im][in][j] * s + bias;
                long idx = (z < 2) ? ((long)(bh * 2048 + ss) * 64 + d)
                                   : ((long)(bh * 64 + d) * 2048 + ss);
                dst[idx] = f2bf(val);
            }
        }
    }
}

// ---------------------------------------------------------------------------
// Attention: per (q-tile of 128, bh). 512 threads = 8 waves, each wave owns
// 16 q-rows (2x the wave-parallelism of the previous version at identical
// global/LDS traffic totals -> hides barrier/LDS latency).
//
// No-max softmax (scores bounded): accumulate exp2(s')@V unnormalized with
// s' pre-scaled by log2(e)/8 at QKV time; denominator = running f32 sum of
// the bf16-ROUNDED P values (consistent with the numerator MFMA input).
//
// QK^T computed SWAPPED: S^T = mfma(K_frag, Q_frag) so lane (quad,ln) holds
// q=ln and 4 consecutive keys -> P store is one ds_write_b64.
// ---------------------------------------------------------------------------
#define LDP 72

__global__ void __launch_bounds__(512)
attn_kernel(const u16* __restrict__ q_ws, const u16* __restrict__ k_ws,
            const u16* __restrict__ v_ws, u16* __restrict__ ctx) {
    __shared__ u16 Kt[64 * LDP];    // [key][d]
    __shared__ u16 Vt[64 * LDP];    // [d][key]
    __shared__ u16 Pt[128 * LDP];   // [q][key] exp(scores) in bf16

    const int tid = threadIdx.x;
    const int wid = tid >> 6, lane = tid & 63, quad = lane >> 4, ln = lane & 15;
    const int bh = blockIdx.y;
    const int q0 = blockIdx.x * 128;
    const u16* qbase = q_ws + (long)bh * 2048 * 64;
    const u16* kbase = k_ws + (long)bh * 2048 * 64;
    const u16* vbase = v_ws + (long)bh * 64 * 2048;

    // Q fragments held in registers for the whole K loop
    bf16x8 aq[2];
#pragma unroll
    for (int ks = 0; ks < 2; ks++)
        aq[ks] = *reinterpret_cast<const bf16x8*>(
            qbase + (long)(q0 + wid * 16 + ln) * 64 + ks * 32 + quad * 8);

    f32x4 acc_o[4];
    float lsum = 0.f;
#pragma unroll
    for (int dt = 0; dt < 4; dt++) acc_o[dt] = (f32x4){0.f, 0.f, 0.f, 0.f};

    // prefetch first K/V tile into registers (512 threads cover 64x64 exactly)
    const int srow = tid >> 3, skc = tid & 7;
    u16x8 kreg = *reinterpret_cast<const u16x8*>(kbase + (long)srow * 64 + skc * 8);
    u16x8 vreg = *reinterpret_cast<const u16x8*>(vbase + (long)srow * 2048 + skc * 8);

    for (int kt = 0; kt < 2048; kt += 64) {
        *reinterpret_cast<u16x8*>(Kt + srow * LDP + skc * 8) = kreg;
        *reinterpret_cast<u16x8*>(Vt + srow * LDP + skc * 8) = vreg;
        if (kt + 64 < 2048) {
            kreg = *reinterpret_cast<const u16x8*>(kbase + (long)(kt + 64 + srow) * 64 + skc * 8);
            vreg = *reinterpret_cast<const u16x8*>(vbase + (long)srow * 2048 + (kt + 64) + skc * 8);
        }
        __syncthreads();

        // S^T = K Q^T (swapped). Lane (quad,ln): q = ln, keys = k8*16+quad*4+j
#pragma unroll
        for (int k8 = 0; k8 < 4; k8++) {
            bf16x8 a0 = *reinterpret_cast<const bf16x8*>(Kt + (k8 * 16 + ln) * LDP + quad * 8);
            bf16x8 a1 = *reinterpret_cast<const bf16x8*>(Kt + (k8 * 16 + ln) * LDP + 32 + quad * 8);
            f32x4 t = (f32x4){0.f, 0.f, 0.f, 0.f};
            t = __builtin_amdgcn_mfma_f32_16x16x32_bf16(a0, aq[0], t, 0, 0, 0);
            t = __builtin_amdgcn_mfma_f32_16x16x32_bf16(a1, aq[1], t, 0, 0, 0);
            // bare v_exp_f32 (log2e folded into q); compiler-path bf16 casts
            __bf16 p0 = (__bf16)__builtin_amdgcn_exp2f(t[0]);
            __bf16 p1 = (__bf16)__builtin_amdgcn_exp2f(t[1]);
            __bf16 p2 = (__bf16)__builtin_amdgcn_exp2f(t[2]);
            __bf16 p3 = (__bf16)__builtin_amdgcn_exp2f(t[3]);
            // denominator sums the ROUNDED values (consistent with PV input)
            lsum += (float)p0 + (float)p1 + (float)p2 + (float)p3;
            *reinterpret_cast<bf16x4*>(Pt + (wid * 16 + ln) * LDP + k8 * 16 + quad * 4)
                = (bf16x4){p0, p1, p2, p3};
        }

        // O += P V   (A-frag reads of Pt are wave-local rows: no barrier needed)
#pragma unroll
        for (int step = 0; step < 2; step++) {
            bf16x8 ap = *reinterpret_cast<const bf16x8*>(
                Pt + (wid * 16 + ln) * LDP + step * 32 + quad * 8);
#pragma unroll
            for (int dt = 0; dt < 4; dt++) {
                bf16x8 bv = *reinterpret_cast<const bf16x8*>(
                    Vt + (dt * 16 + ln) * LDP + step * 32 + quad * 8);
                acc_o[dt] = __builtin_amdgcn_mfma_f32_16x16x32_bf16(ap, bv, acc_o[dt], 0, 0, 0);
            }
        }
        __syncthreads();
    }

    // finalize denominator and write ctx [t][h*64+d] bf16
    const int b = bh >> 4, h = bh & 15;
    // lane (quad,ln) has partial sum (16 keys/iter) for q-row ln; reduce quads
    float lt = lsum;
    lt += __shfl_xor(lt, 16, 64);
    lt += __shfl_xor(lt, 32, 64);
    // lt now = full denominator for q = q0 + wid*16 + ln (all lanes)
#pragma unroll
    for (int j = 0; j < 4; j++) {
        // acc_o rows live at q = quad*4 + j; fetch matching denominator
        float rinv = 1.0f / __shfl(lt, quad * 4 + j, 64);
        int t = b * 2048 + q0 + wid * 16 + quad * 4 + j;
#pragma unroll
        for (int dt = 0; dt < 4; dt++) {
            float val = acc_o[dt][j] * rinv;
            ctx[(long)t * 1024 + h * 64 + dt * 16 + ln] = f2bf(val);
        }
    }
}

// ---------------------------------------------------------------------------
// Output projection: d_out[t][o] = ctx @ wo^T * s_o + b_o  (fp32 out)
// ---------------------------------------------------------------------------
__global__ void o_gemm(const u16* __restrict__ ctx, const u16* __restrict__ wo,
                       const float* __restrict__ so, const float* __restrict__ bo,
                       float* __restrict__ out) {
    __shared__ __align__(16) u16 As[128 * 64];
    __shared__ __align__(16) u16 Bs[128 * 64];
    const int t0 = blockIdx.x * 128, n0 = blockIdx.y * 128;
    f32x4 acc[4][4];
    gemm_mainloop(ctx, wo, t0, n0, As, Bs, acc);

    const int tid = threadIdx.x;
    const int wid = tid >> 6, lane = tid & 63, quad = lane >> 4, ln = lane & 15;
    const int wm = wid >> 1, wn = wid & 1;
    const float s = so[0];
#pragma unroll
    for (int in = 0; in < 4; in++) {
        int col = n0 + wn * 64 + in * 16 + ln;
        float bias = bo[col];
#pragma unroll
        for (int im = 0; im < 4; im++) {
            int rbase = t0 + wm * 64 + im * 16 + quad * 4;
#pragma unroll
            for (int j = 0; j < 4; j++)
                out[(long)(rbase + j) * 1024 + col] = acc[im][in][j] * s + bias;
        }
    }
}

// ---------------------------------------------------------------------------
extern "C" void kernel_launch(void* const* d_in, const int* in_sizes, int n_in,
                              void* d_out, int out_size, void* d_ws, size_t ws_size,
                              hipStream_t stream) {
    const float* x   = (const float*)d_in[0];
    const float* w_q = (const float*)d_in[1];
    const float* s_q = (const float*)d_in[2];
    const float* b_q = (const float*)d_in[3];
    const float* w_k = (const float*)d_in[4];
    const float* s_k = (const float*)d_in[5];
    const float* b_k = (const float*)d_in[6];
    const float* w_v = (const float*)d_in[7];
    const float* s_v = (const float*)d_in[8];
    const float* b_v = (const float*)d_in[9];
    const float* w_o = (const float*)d_in[10];
    const float* s_o = (const float*)d_in[11];
    const float* b_o = (const float*)d_in[12];

    if (ws_size < (size_t)50331648) return;  // need 48 MB of scratch

    u16* ws     = (u16*)d_ws;
    u16* x_bf   = ws;                    // 4096*1024
    u16* wq_bf  = x_bf  + 4194304;       // 1024*1024 each
    u16* wk_bf  = wq_bf + 1048576;
    u16* wv_bf  = wk_bf + 1048576;
    u16* wo_bf  = wv_bf + 1048576;
    u16* q_ws   = wo_bf + 1048576;       // [32 bh][2048 s][64 d]
    u16* k_ws   = q_ws  + 4194304;
    u16* v_ws   = k_ws  + 4194304;       // [32 bh][64 d][2048 s]
    u16* ctx_ws = v_ws  + 4194304;       // [4096 t][1024]

    convert_kernel<<<dim3(8192), dim3(256), 0, stream>>>(x, w_q, w_k, w_v, w_o, ws);
    qkv_gemm<<<dim3(32, 8, 3), dim3(256), 0, stream>>>(x_bf, wq_bf, wk_bf, wv_bf,
                                                       s_q, s_k, s_v, b_q, b_k, b_v,
                                                       q_ws, k_ws, v_ws);
    attn_kernel<<<dim3(16, 32), dim3(512), 0, stream>>>(q_ws, k_ws, v_ws, ctx_ws);
    o_gemm<<<dim3(32, 8), dim3(256), 0, stream>>>(ctx_ws, wo_bf, s_o, b_o, (float*)d_out);
}